// Round 15
// baseline (233.208 us; speedup 1.0000x reference)
//
#include <hip/hip_runtime.h>
#include <math.h>

// SymNet fused model. L=1 collapses the mamba block to:
//   u = rmsnorm(h); xz = u@Wi; x = silu(xz[:,:1024]*cw[:,3]+cb); z' = silu(xz[:,1024:])
//   xdbl = x@Wx; dt = softplus(xdbl[:,:32]@Wdt + bdt); bc = dot(xdbl[:,32:48], xdbl[:,48:64])
//   g = x*(dt*bc + D) * z'; h += g@Wo
// A_log (dA) is dead code: dA multiplies h0 == 0.
// R15: inproj -> BM=256 x BN=128, 512 threads, dbuf 2-phase (staging 256->192 MB,
//      same 8 waves/CU). In-GEMM sumsq re-indexed for 256-row tiles. Rest = R14.

typedef __bf16 bf16x8 __attribute__((ext_vector_type(8)));
typedef float f32x4 __attribute__((ext_vector_type(4)));
typedef short short8 __attribute__((ext_vector_type(8)));

__device__ __forceinline__ float siluf(float v){ return v / (1.f + __expf(-v)); }
__device__ __forceinline__ float spfast(float v){ return v > 15.f ? v : __logf(1.f + __expf(v)); }
__device__ __forceinline__ float b2f(unsigned short u){ return __uint_as_float(((unsigned)u)<<16); }
__device__ __forceinline__ unsigned short f2b(float f){
  unsigned u = __float_as_uint(f);
  return (unsigned short)((u + 0x7fffu + ((u>>16)&1u)) >> 16);
}
__device__ __forceinline__ void g2l16(const void* g, void* l){
  __builtin_amdgcn_global_load_lds((const __attribute__((address_space(1))) unsigned int*)g,
                                   (__attribute__((address_space(3))) unsigned int*)l, 16, 0, 0);
}

// ---------------- merged prep: weight transposes (+norm folds) + heads concat + conv ----------------
__global__ __launch_bounds__(256) void k_wt_all(
    const float* __restrict__ in_proj_w, const float* __restrict__ out_proj_w,
    const float* __restrict__ x_proj_w,  const float* __restrict__ dt_proj_w,
    const float* __restrict__ enc_w,     const float* __restrict__ proj_w,
    const float* __restrict__ act_w, const float* __restrict__ comm_w, const float* __restrict__ val_w,
    const float* __restrict__ norm_w, const float* __restrict__ final_nw,
    const float* __restrict__ obs, const float* __restrict__ comm_in,
    const float* __restrict__ conv_w, const float* __restrict__ conv_b,
    unsigned short* __restrict__ wi_t, unsigned short* __restrict__ wo_t,
    unsigned short* __restrict__ wx_t, unsigned short* __restrict__ wdt_t,
    unsigned short* __restrict__ we_t, unsigned short* __restrict__ wp_t,
    unsigned short* __restrict__ wh_t,
    unsigned short* __restrict__ v, unsigned short* __restrict__ cat)
{
  int b = blockIdx.x;
  const int t = threadIdx.x;

  // frontend prep segment: blocks 3792..4815 (1024 blocks, 8 rows each)
  if (b >= 3792) {
    __shared__ float s_obs[8][76];
    const int r0 = (b - 3792) * 8;
    for (int i = t; i < 8*75; i += 256) s_obs[i/75][i%75] = obs[(size_t)(r0 + i/75)*75 + i%75];
    __syncthreads();
    for (int i = t; i < 8*288; i += 256) {
      int r = i / 288, o = i % 288;
      int c = o / 9, ij = o % 9, oi = ij/3, oj = ij%3;
      float acc = conv_b[c];
      #pragma unroll
      for (int ic=0; ic<3; ic++)
        #pragma unroll
        for (int ki=0; ki<3; ki++)
          #pragma unroll
          for (int kj=0; kj<3; kj++)
            acc = fmaf(s_obs[r][ic*25 + (oi+ki)*5 + (oj+kj)], conv_w[((c*3+ic)*3+ki)*3+kj], acc);
      v[(size_t)(r0+r)*320 + o] = f2b(fmaxf(acc, 0.f));
    }
    v[(size_t)(r0 + (t>>5))*320 + 288 + (t&31)] = 0;  // zero pad cols 288..319
    for (int i = t; i < 8*128; i += 256) {
      int r = i >> 7, c = i & 127;
      cat[(size_t)(r0+r)*384 + 256 + c] = f2b(comm_in[(size_t)(r0+r)*128 + c]);
    }
    return;
  }
  // heads concat segment: blocks 3536..3791 (final_nw folded, fp32)
  if (b >= 3536) {
    const int n = b - 3536;
    for (int k = t; k < 512; k += 256) {
      float v2;
      if (n < 4)         v2 = act_w[k*4 + n];
      else if (n < 132)  v2 = comm_w[k*128 + (n-4)];
      else if (n == 132) v2 = val_w[k];
      else               v2 = 0.f;
      wh_t[(size_t)n*512 + k] = f2b(v2 * final_nw[k]);
    }
    return;
  }
  const float* Wsrc; unsigned short* Wdst; int Kd, Nd, KP, nkb;
  const float* nwf = nullptr;  // per-k fold factor (norm_w), or null
  if (b < 2048) {        // in_proj, 2 layers: [512][2048] -> [2048][512], norm_w folded
    const int L = b >> 10; b &= 1023;
    Wsrc = in_proj_w + (size_t)L*512*2048; Wdst = wi_t + (size_t)L*2048*512;
    Kd = 512; Nd = 2048; KP = 512; nkb = 16;
    nwf = norm_w + L*512;
  } else if (b < 3072) { // out_proj, 2 layers: [1024][512] -> [512][1024]
    b -= 2048; const int L = b >> 9; b &= 511;
    Wsrc = out_proj_w + (size_t)L*1024*512; Wdst = wo_t + (size_t)L*512*1024;
    Kd = 1024; Nd = 512; KP = 1024; nkb = 32;
  } else if (b < 3200) { // x_proj, 2 layers: [1024][64] -> [64][1024]
    b -= 3072; const int L = b >> 6; b &= 63;
    Wsrc = x_proj_w + (size_t)L*1024*64; Wdst = wx_t + (size_t)L*64*1024;
    Kd = 1024; Nd = 64; KP = 1024; nkb = 32;
  } else if (b < 3264) { // dt_proj, 2 layers: [32][1024] -> [1024][32]
    b -= 3200; const int L = b >> 5; b &= 31;
    Wsrc = dt_proj_w + (size_t)L*32*1024; Wdst = wdt_t + (size_t)L*1024*32;
    Kd = 32; Nd = 1024; KP = 32; nkb = 1;
  } else if (b < 3344) { // enc: [288][256] -> [256][320] (K padded)
    b -= 3264; Wsrc = enc_w; Wdst = we_t; Kd = 288; Nd = 256; KP = 320; nkb = 10;
  } else {               // proj: [384][512] -> [512][384]
    b -= 3344; Wsrc = proj_w; Wdst = wp_t; Kd = 384; Nd = 512; KP = 384; nkb = 12;
  }
  __shared__ float s[32][33];
  const int kb = (b % nkb)*32, nb = (b / nkb)*32;
  const int c = t & 31, r = t >> 5;
  #pragma unroll
  for (int i=0;i<32;i+=8) {
    const int k = kb + r + i;
    s[r+i][c] = (k < Kd) ? Wsrc[(size_t)k*Nd + nb + c] : 0.f;
  }
  __syncthreads();
  const float nwv = nwf ? nwf[kb + c] : 1.f;   // written value has k = kb + c
  #pragma unroll
  for (int i=0;i<32;i+=8) Wdst[(size_t)(nb+r+i)*KP + kb + c] = f2b(s[c][r+i] * nwv);
}

// ---------------- MFMA 128xNB tile mainloop, double-buffered (T3 minimum 2-phase) ----------------
template<int K, int NB>
__device__ __forceinline__ void gemmT(const unsigned short* __restrict__ A,
                                      const unsigned short* __restrict__ Bt,
                                      int r0, int c0,
                                      unsigned short* sA, unsigned short* sB,
                                      f32x4 (&acc)[4][NB/32])
{
  constexpr int NF = NB/32;
  constexpr int ABUF = 128*64, BBUF = NB*64;
  const int tid = threadIdx.x;
  const int l = tid & 63;
  const int wr = (tid>>7)&1, wc = (tid>>6)&1;
  const int rowA = tid>>3, kc8 = (tid&7)*8;
  const unsigned short* gA = A  + (size_t)(r0+rowA)*K + kc8;
  const unsigned short* gB = Bt + (size_t)(c0+rowA)*K + kc8;
  const int aOff = (wr*64 + (l&15))*64 + ((l>>4)*8);
  const int bOff = (wc*(NB/2) + (l&15))*64 + ((l>>4)*8);

  auto stage = [&](int kt, int buf) {
    #pragma unroll
    for (int it=0; it<4; ++it)
      g2l16(gA + (size_t)(it*32)*K + kt, sA + buf*ABUF + (it*256+tid)*8);
    #pragma unroll
    for (int it=0; it<NF; ++it)
      g2l16(gB + (size_t)(it*32)*K + kt, sB + buf*BBUF + (it*256+tid)*8);
  };

  stage(0, 0);
  __syncthreads();
  int cur = 0;
  for (int kt=0; kt<K; kt+=64) {
    if (kt + 64 < K) stage(kt + 64, cur ^ 1);   // in flight during MFMA below
    const unsigned short* pA = sA + cur*ABUF;
    const unsigned short* pB = sB + cur*BBUF;
    #pragma unroll
    for (int ks=0; ks<64; ks+=32) {
      bf16x8 af[4], bfm[NF];
      #pragma unroll
      for (int m=0;m<4;m++) af[m]  = *(const bf16x8*)(pA + (m*16)*64 + aOff + ks);
      #pragma unroll
      for (int n=0;n<NF;n++) bfm[n] = *(const bf16x8*)(pB + (n*16)*64 + bOff + ks);
      #pragma unroll
      for (int m=0;m<4;m++)
        #pragma unroll
        for (int n=0;n<NF;n++)
          acc[m][n] = __builtin_amdgcn_mfma_f32_16x16x32_bf16(af[m], bfm[n], acc[m][n], 0, 0, 0);
    }
    __syncthreads();
    cur ^= 1;
  }
}

// ---------------- in_proj: 256x128 tile, 512 threads, dbuf, in-GEMM row-sumsq ----------------
// waves: 4M x 2N; per-wave 64x64 output. A staged 192MB total vs 256MB at 128x128.
__global__ __launch_bounds__(512) void k_gemm_inproj(
    const unsigned short* __restrict__ A, const unsigned short* __restrict__ Bt,
    const float* __restrict__ cw, const float* __restrict__ cb,
    unsigned short* __restrict__ xs, unsigned short* __restrict__ zs)
{
  constexpr int K = 512, ABUF = 256*64, BBUF = 128*64;
  __shared__ unsigned short sA[2*ABUF], sB[2*BBUF];   // 64KB + 32KB
  __shared__ float s_scale[256];
  f32x4 acc[4][4];
  #pragma unroll
  for (int m=0;m<4;m++)
    #pragma unroll
    for (int n=0;n<4;n++) acc[m][n] = (f32x4){0.f,0.f,0.f,0.f};
  const int tid = threadIdx.x, l = tid & 63;
  const int w = tid >> 6, wr = w >> 1, wc = w & 1;   // 4M x 2N
  const int r0 = blockIdx.x*256, c0 = blockIdx.y*128;
  const int rowA = tid>>3, kc8 = (tid&7)*8;          // rowA 0..63
  const unsigned short* gA = A  + (size_t)(r0+rowA)*K + kc8;
  const unsigned short* gB = Bt + (size_t)(c0+rowA)*K + kc8;
  const int aOff = (wr*64 + (l&15))*64 + ((l>>4)*8);
  const int bOff = (wc*64 + (l&15))*64 + ((l>>4)*8);

  auto stage = [&](int kt, int buf) {
    #pragma unroll
    for (int it=0; it<4; ++it)   // A: 256 rows
      g2l16(gA + (size_t)(it*64)*K + kt, sA + buf*ABUF + (it*512+tid)*8);
    #pragma unroll
    for (int it=0; it<2; ++it)   // B: 128 rows
      g2l16(gB + (size_t)(it*64)*K + kt, sB + buf*BBUF + (it*512+tid)*8);
  };

  float ss4[4] = {0.f,0.f,0.f,0.f};
  stage(0, 0);
  __syncthreads();
  int cur = 0;
  for (int kt=0; kt<K; kt+=64) {
    if (kt + 64 < K) stage(kt + 64, cur ^ 1);
    const unsigned short* pA = sA + cur*ABUF;
    const unsigned short* pB = sB + cur*BBUF;
    #pragma unroll
    for (int ks=0; ks<64; ks+=32) {
      bf16x8 af[4], bfm[4];
      #pragma unroll
      for (int m=0;m<4;m++) af[m]  = *(const bf16x8*)(pA + (m*16)*64 + aOff + ks);
      #pragma unroll
      for (int n=0;n<4;n++) bfm[n] = *(const bf16x8*)(pB + (n*16)*64 + bOff + ks);
      #pragma unroll
      for (int m=0;m<4;m++)
        #pragma unroll
        for (int n=0;n<4;n++)
          acc[m][n] = __builtin_amdgcn_mfma_f32_16x16x32_bf16(af[m], bfm[n], acc[m][n], 0, 0, 0);
    }
    // per-row sumsq of this K-slice (rows (tid>>3)+c2*64)
    #pragma unroll
    for (int c2=0;c2<4;c2++){
      short8 av = *(const short8*)(pA + (tid + c2*512)*8);
      #pragma unroll
      for (int e=0;e<8;e++){ float f = b2f((unsigned short)av[e]); ss4[c2] = fmaf(f, f, ss4[c2]); }
    }
    __syncthreads();
    cur ^= 1;
  }
  #pragma unroll
  for (int c2=0;c2<4;c2++){
    #pragma unroll
    for (int msk=1; msk<8; msk<<=1) ss4[c2] += __shfl_xor(ss4[c2], msk, 64);
  }
  if ((tid & 7) == 0) {
    #pragma unroll
    for (int c2=0;c2<4;c2++)
      s_scale[(tid>>3) + c2*64] = rsqrtf(ss4[c2]*(1.f/512.f) + 1e-5f);
  }
  __syncthreads();

  const int colB = c0 + wc*64 + (l&15);
  const int rowL = wr*64 + ((l>>4)*4);
  float sv[4][4];
  #pragma unroll
  for (int m=0;m<4;m++)
    #pragma unroll
    for (int j=0;j<4;j++) sv[m][j] = s_scale[rowL + m*16 + j];
  if (c0 < 1024) {
    #pragma unroll
    for (int n=0;n<4;n++){
      const int col = colB + n*16;
      const float cw3 = cw[col*4+3], cbv = cb[col];
      #pragma unroll
      for (int m=0;m<4;m++)
        #pragma unroll
        for (int j=0;j<4;j++){
          const int row = r0 + rowL + m*16 + j;
          xs[(size_t)row*1024 + col] = f2b(siluf(fmaf(acc[m][n][j]*sv[m][j], cw3, cbv)));
        }
    }
  } else {
    #pragma unroll
    for (int n=0;n<4;n++){
      const int col = colB + n*16 - 1024;
      #pragma unroll
      for (int m=0;m<4;m++)
        #pragma unroll
        for (int j=0;j<4;j++){
          const int row = r0 + rowL + m*16 + j;
          zs[(size_t)row*1024 + col] = f2b(siluf(acc[m][n][j]*sv[m][j]));
        }
    }
  }
}

// ---------------- gemmT_ss for heads (128-row tiles, K=512) ----------------
template<int K, int NB>
__device__ __forceinline__ void gemmT_ss(const unsigned short* __restrict__ A,
                                         const unsigned short* __restrict__ Bt,
                                         int r0, int c0,
                                         unsigned short* sA, unsigned short* sB,
                                         f32x4 (&acc)[4][NB/32], float* s_scale)
{
  constexpr int NF = NB/32;
  constexpr int ABUF = 128*64, BBUF = NB*64;
  const int tid = threadIdx.x;
  const int l = tid & 63;
  const int wr = (tid>>7)&1, wc = (tid>>6)&1;
  const int rowA = tid>>3, kc8 = (tid&7)*8;
  const unsigned short* gA = A  + (size_t)(r0+rowA)*K + kc8;
  const unsigned short* gB = Bt + (size_t)(c0+rowA)*K + kc8;
  const int aOff = (wr*64 + (l&15))*64 + ((l>>4)*8);
  const int bOff = (wc*(NB/2) + (l&15))*64 + ((l>>4)*8);

  auto stage = [&](int kt, int buf) {
    #pragma unroll
    for (int it=0; it<4; ++it)
      g2l16(gA + (size_t)(it*32)*K + kt, sA + buf*ABUF + (it*256+tid)*8);
    #pragma unroll
    for (int it=0; it<NF; ++it)
      g2l16(gB + (size_t)(it*32)*K + kt, sB + buf*BBUF + (it*256+tid)*8);
  };

  float ss4[4] = {0.f, 0.f, 0.f, 0.f};
  stage(0, 0);
  __syncthreads();
  int cur = 0;
  for (int kt=0; kt<K; kt+=64) {
    if (kt + 64 < K) stage(kt + 64, cur ^ 1);
    const unsigned short* pA = sA + cur*ABUF;
    const unsigned short* pB = sB + cur*BBUF;
    #pragma unroll
    for (int ks=0; ks<64; ks+=32) {
      bf16x8 af[4], bfm[NF];
      #pragma unroll
      for (int m=0;m<4;m++) af[m]  = *(const bf16x8*)(pA + (m*16)*64 + aOff + ks);
      #pragma unroll
      for (int n=0;n<NF;n++) bfm[n] = *(const bf16x8*)(pB + (n*16)*64 + bOff + ks);
      #pragma unroll
      for (int m=0;m<4;m++)
        #pragma unroll
        for (int n=0;n<NF;n++)
          acc[m][n] = __builtin_amdgcn_mfma_f32_16x16x32_bf16(af[m], bfm[n], acc[m][n], 0, 0, 0);
    }
    #pragma unroll
    for (int c2=0;c2<4;c2++){
      short8 av = *(const short8*)(pA + (tid + c2*256)*8);
      #pragma unroll
      for (int e=0;e<8;e++){ float f = b2f((unsigned short)av[e]); ss4[c2] = fmaf(f, f, ss4[c2]); }
    }
    __syncthreads();
    cur ^= 1;
  }
  #pragma unroll
  for (int c2=0;c2<4;c2++){
    #pragma unroll
    for (int msk=1; msk<8; msk<<=1) ss4[c2] += __shfl_xor(ss4[c2], msk, 64);
  }
  if ((tid & 7) == 0) {
    #pragma unroll
    for (int c2=0;c2<4;c2++)
      s_scale[(tid>>3) + c2*32] = rsqrtf(ss4[c2]*(1.f/512.f) + 1e-5f);
  }
  __syncthreads();
}

// ---------------- out_proj: g(8192x1024) @ Wo -> hb += (fp32 add, bf16 store) ----------------
__global__ __launch_bounds__(256) void k_gemm_outproj(
    const unsigned short* __restrict__ A, const unsigned short* __restrict__ Bt,
    unsigned short* __restrict__ hb)
{
  __shared__ unsigned short sA[2*128*64], sB[2*64*64];
  f32x4 acc[4][2];
  #pragma unroll
  for (int m=0;m<4;m++)
    #pragma unroll
    for (int n=0;n<2;n++) acc[m][n] = (f32x4){0.f,0.f,0.f,0.f};
  const int r0 = blockIdx.x*128, c0 = blockIdx.y*64;
  gemmT<1024,64>(A, Bt, r0, c0, sA, sB, acc);

  const int tid = threadIdx.x, l = tid & 63;
  const int wr = (tid>>7)&1, wc = (tid>>6)&1;
  const int colB = c0 + wc*32 + (l&15);
  const int rowB = r0 + wr*64 + ((l>>4)*4);
  #pragma unroll
  for (int n=0;n<2;n++){
    const int col = colB + n*16;
    #pragma unroll
    for (int m=0;m<4;m++)
      #pragma unroll
      for (int j=0;j<4;j++){
        const int row = rowB + m*16 + j;
        float hv = b2f(hb[(size_t)row*512 + col]) + acc[m][n][j];
        hb[(size_t)row*512 + col] = f2b(hv);
      }
  }
}

// ---------------- frontend GEMM1: v(8192x320) @ enc_t^T -> relu -> cat[:, :256] (BN=64) ----------------
__global__ __launch_bounds__(256) void k_gemm_enc(
    const unsigned short* __restrict__ A, const unsigned short* __restrict__ Bt,
    const float* __restrict__ bias, unsigned short* __restrict__ cat)
{
  __shared__ unsigned short sA[2*128*64], sB[2*64*64];
  f32x4 acc[4][2];
  #pragma unroll
  for (int m=0;m<4;m++)
    #pragma unroll
    for (int n=0;n<2;n++) acc[m][n] = (f32x4){0.f,0.f,0.f,0.f};
  const int r0 = blockIdx.x*128, c0 = blockIdx.y*64;
  gemmT<320,64>(A, Bt, r0, c0, sA, sB, acc);

  const int tid = threadIdx.x, l = tid & 63;
  const int wr = (tid>>7)&1, wc = (tid>>6)&1;
  const int colB = c0 + wc*32 + (l&15);
  const int rowB = r0 + wr*64 + ((l>>4)*4);
  #pragma unroll
  for (int n=0;n<2;n++){
    const int col = colB + n*16;
    const float bv = bias[col];
    #pragma unroll
    for (int m=0;m<4;m++)
      #pragma unroll
      for (int j=0;j<4;j++){
        const size_t row = rowB + m*16 + j;
        cat[row*384 + col] = f2b(fmaxf(acc[m][n][j] + bv, 0.f));
      }
  }
}

// ---------------- frontend GEMM2: cat(8192x384) @ proj_t^T -> relu -> hb bf16 (BN=64) ----------------
__global__ __launch_bounds__(256) void k_gemm_proj(
    const unsigned short* __restrict__ A, const unsigned short* __restrict__ Bt,
    const float* __restrict__ bias, unsigned short* __restrict__ hb)
{
  __shared__ unsigned short sA[2*128*64], sB[2*64*64];
  f32x4 acc[4][2];
  #pragma unroll
  for (int m=0;m<4;m++)
    #pragma unroll
    for (int n=0;n<2;n++) acc[m][n] = (f32x4){0.f,0.f,0.f,0.f};
  const int r0 = blockIdx.x*128, c0 = blockIdx.y*64;
  gemmT<384,64>(A, Bt, r0, c0, sA, sB, acc);

  const int tid = threadIdx.x, l = tid & 63;
  const int wr = (tid>>7)&1, wc = (tid>>6)&1;
  const int colB = c0 + wc*32 + (l&15);
  const int rowB = r0 + wr*64 + ((l>>4)*4);
  #pragma unroll
  for (int n=0;n<2;n++){
    const int col = colB + n*16;
    const float bv = bias[col];
    #pragma unroll
    for (int m=0;m<4;m++)
      #pragma unroll
      for (int j=0;j<4;j++){
        const size_t row = rowB + m*16 + j;
        hb[row*512 + col] = f2b(fmaxf(acc[m][n][j] + bv, 0.f));
      }
  }
}

// ---------------- heads GEMM: hb @ (Wh*fnw)^T -> scale s[r] -> act/tanh/val scatter ----------------
__global__ __launch_bounds__(256) void k_gemm_heads(
    const unsigned short* __restrict__ A, const unsigned short* __restrict__ Bt,
    const float* __restrict__ act_b, const float* __restrict__ comm_b,
    const float* __restrict__ val_b, float* __restrict__ out)
{
  __shared__ unsigned short sA[2*128*64], sB[2*64*64];
  __shared__ float s_scale[128];
  f32x4 acc[4][2];
  #pragma unroll
  for (int m=0;m<4;m++)
    #pragma unroll
    for (int n=0;n<2;n++) acc[m][n] = (f32x4){0.f,0.f,0.f,0.f};
  const int r0 = blockIdx.x*128, c0 = blockIdx.y*64;
  gemmT_ss<512,64>(A, Bt, r0, c0, sA, sB, acc, s_scale);

  const int tid = threadIdx.x, l = tid & 63;
  const int wr = (tid>>7)&1, wc = (tid>>6)&1;
  const int colB = c0 + wc*32 + (l&15);
  const int rowL = wr*64 + ((l>>4)*4);
  #pragma unroll
  for (int n=0;n<2;n++){
    const int col = colB + n*16;
    if (col > 132) continue;
    #pragma unroll
    for (int m=0;m<4;m++)
      #pragma unroll
      for (int j=0;j<4;j++){
        const size_t row = r0 + rowL + m*16 + j;
        float v = acc[m][n][j] * s_scale[rowL + m*16 + j];
        if (col < 4)        out[row*4 + col] = v + act_b[col];
        else if (col < 132) out[32768 + row*128 + (col-4)] = tanhf(v + comm_b[col-4]);
        else                out[1081344 + row] = v + val_b[0];
      }
  }
}

// ---------------- fused SSM: x_dbl GEMM + bc + dt GEMM + gate, 32 rows/block (dbuf both phases) ----------------
__global__ __launch_bounds__(256) void k_ssm_f(
    unsigned short* __restrict__ xs, const unsigned short* __restrict__ zs,
    const unsigned short* __restrict__ Wx_t, const unsigned short* __restrict__ Wdt_t,
    const float* __restrict__ bdt, const float* __restrict__ Dp)
{
  __shared__ unsigned short sX[32*1024];   // 64KB: xs rows, bf16
  __shared__ unsigned short sB[2*64*128];  // 32KB: Wx chunks (ph1) / Wdt chunks [256][32] (ph2), dbuf
  __shared__ float s_dbl[32][64];          //  8KB
  __shared__ unsigned short sDt[32*32];    //  2KB
  __shared__ float s_bc[32];
  constexpr int BB = 64*128;
  const int tid = threadIdx.x, l = tid & 63, w = tid >> 6;
  const int r0 = blockIdx.x * 32;

  auto stageWx = [&](int kt, int buf) {
    #pragma unroll
    for (int it=0; it<4; ++it) {               // 64 rows x 128 k
      const int idx = it*256 + tid;
      g2l16(Wx_t + (size_t)(idx>>4)*1024 + (idx&15)*8 + kt, sB + buf*BB + idx*8);
    }
  };

  // stage all 32 xs rows (16 iters x 256 threads x 16B) + first Wx chunk
  #pragma unroll
  for (int it=0; it<16; ++it) {
    const int idx = it*256 + tid;              // row = idx>>7, col8 = (idx&127)*8
    g2l16(xs + (size_t)(r0 + (idx>>7))*1024 + (idx&127)*8, sX + idx*8);
  }
  stageWx(0, 0);
  __syncthreads();

  // ---- phase 1: x_dbl = xs @ Wx_t^T (64 cols; wave w owns cols w*16..w*16+15) ----
  f32x4 acc0 = (f32x4){0.f,0.f,0.f,0.f}, acc1 = (f32x4){0.f,0.f,0.f,0.f};
  int cur = 0;
  for (int kt = 0; kt < 1024; kt += 128) {
    if (kt + 128 < 1024) stageWx(kt + 128, cur ^ 1);
    const unsigned short* pB = sB + cur*BB;
    #pragma unroll
    for (int ks=0; ks<128; ks+=32) {
      bf16x8 a0 = *(const bf16x8*)(sX + ((l&15))*1024    + (l>>4)*8 + kt + ks);
      bf16x8 a1 = *(const bf16x8*)(sX + (16+(l&15))*1024 + (l>>4)*8 + kt + ks);
      bf16x8 bf = *(const bf16x8*)(pB + (w*16+(l&15))*128 + (l>>4)*8 + ks);
      acc0 = __builtin_amdgcn_mfma_f32_16x16x32_bf16(a0, bf, acc0, 0, 0, 0);
      acc1 = __builtin_amdgcn_mfma_f32_16x16x32_bf16(a1, bf, acc1, 0, 0, 0);
    }
    __syncthreads();
    cur ^= 1;
  }

  // stage first Wdt chunk early (hides under the s_dbl/bc/sDt work)
  auto stageWdt = [&](int c, int buf) {
    const int cc = c*256;
    #pragma unroll
    for (int it=0; it<4; ++it) {               // 256 rows x 32 k = 16KB
      const int idx = it*256 + tid;            // row = idx>>2, col8 = (idx&3)*8
      g2l16(Wdt_t + (size_t)(cc + (idx>>2))*32 + (idx&3)*8, sB + buf*BB + idx*8);
    }
  };
  stageWdt(0, 0);

  #pragma unroll
  for (int j=0;j<4;j++) {
    s_dbl[(l>>4)*4 + j]     [w*16 + (l&15)] = acc0[j];
    s_dbl[16 + (l>>4)*4 + j][w*16 + (l&15)] = acc1[j];
  }
  __syncthreads();
  if (tid < 32) {          // bc[row] = dot(xdbl[row][32:48], xdbl[row][48:64])
    float a = 0.f;
    #pragma unroll
    for (int s=0;s<16;s++) a = fmaf(s_dbl[tid][32+s], s_dbl[tid][48+s], a);
    s_bc[tid] = a;
  }
  { // dt_in bf16 [32][32]
    const int r = tid >> 3, c4 = (tid & 7)*4;
    sDt[r*32 + c4]   = f2b(s_dbl[r][c4]);
    sDt[r*32 + c4+1] = f2b(s_dbl[r][c4+1]);
    sDt[r*32 + c4+2] = f2b(s_dbl[r][c4+2]);
    sDt[r*32 + c4+3] = f2b(s_dbl[r][c4+3]);
  }
  __syncthreads();

  // ---- phase 2: dt GEMM (K=32) + gate, 4 chunks of 256 cols; wave w owns 64 cols/chunk ----
  bf16x8 af0 = *(const bf16x8*)(sDt + ((l&15))*32    + (l>>4)*8);
  bf16x8 af1 = *(const bf16x8*)(sDt + (16+(l&15))*32 + (l>>4)*8);
  for (int c = 0; c < 4; ++c) {
    if (c + 1 < 4) stageWdt(c + 1, (c + 1) & 1);
    const unsigned short* pB = sB + (c & 1)*BB;
    f32x4 a2[2][4];
    #pragma unroll
    for (int n=0;n<4;n++){
      bf16x8 bn = *(const bf16x8*)(pB + (w*64 + n*16 + (l&15))*32 + (l>>4)*8);
      a2[0][n] = __builtin_amdgcn_mfma_f32_16x16x32_bf16(af0, bn, (f32x4){0.f,0.f,0.f,0.f}, 0, 0, 0);
      a2[1][n] = __builtin_amdgcn_mfma_f32_16x16x32_bf16(af1, bn, (f32x4){0.f,0.f,0.f,0.f}, 0, 0, 0);
    }
    const int cc = c*256;
    #pragma unroll
    for (int n=0;n<4;n++){
      const int col = cc + w*64 + n*16 + (l&15);
      const float bj = bdt[col], dpj = Dp[col];
      #pragma unroll
      for (int m=0;m<2;m++){
        #pragma unroll
        for (int j=0;j<4;j++){
          const int rloc = m*16 + (l>>4)*4 + j;
          const size_t row = r0 + rloc;
          const float dtv = spfast(a2[m][n][j] + bj);
          const float f = fmaf(dtv, s_bc[rloc], dpj);
          const float x = b2f(sX[rloc*1024 + col]);
          const float z = b2f(zs[row*1024 + col]);
          xs[row*1024 + col] = f2b(x * f * z);
        }
      }
    }
    __syncthreads();
  }
}

extern "C" void kernel_launch(void* const* d_in, const int* in_sizes, int n_in,
                              void* d_out, int out_size, void* d_ws, size_t ws_size,
                              hipStream_t stream) {
  const float* obs       = (const float*)d_in[0];
  const float* comm_in   = (const float*)d_in[1];
  const float* conv_w    = (const float*)d_in[2];
  const float* conv_b    = (const float*)d_in[3];
  const float* enc_w     = (const float*)d_in[4];
  const float* enc_b     = (const float*)d_in[5];
  const float* proj_w    = (const float*)d_in[6];
  const float* proj_b    = (const float*)d_in[7];
  const float* norm_w    = (const float*)d_in[8];
  const float* in_proj_w = (const float*)d_in[9];
  const float* conv1d_w  = (const float*)d_in[10];
  const float* conv1d_b  = (const float*)d_in[11];
  const float* x_proj_w  = (const float*)d_in[12];
  const float* dt_proj_w = (const float*)d_in[13];
  const float* dt_proj_b = (const float*)d_in[14];
  // d_in[15] = A_log: dead at L=1
  const float* D_param   = (const float*)d_in[16];
  const float* out_proj_w= (const float*)d_in[17];
  const float* final_nw  = (const float*)d_in[18];
  const float* act_w     = (const float*)d_in[19];
  const float* act_b     = (const float*)d_in[20];
  const float* comm_w    = (const float*)d_in[21];
  const float* comm_b    = (const float*)d_in[22];
  const float* val_w     = (const float*)d_in[23];
  const float* val_b     = (const float*)d_in[24];
  float* out = (float*)d_out;

  char* W = (char*)d_ws;
  unsigned short* hb   = (unsigned short*)(W + (16u<<20));        //  8 MB bf16 residual h
  unsigned short* xs_b = (unsigned short*)(W + (24u<<20));        // 16 MB (reused as g; v_b during frontend)
  unsigned short* zs_b = (unsigned short*)(W + (40u<<20));        // 16 MB (cat_b during frontend)
  unsigned short* wi_t = (unsigned short*)(W + (56u<<20));        //  4 MB (2 layers, [2048][512], norm folded)
  unsigned short* wo_t = (unsigned short*)(W + (60u<<20));        //  2 MB (2 layers, [512][1024])
  unsigned short* wx_t = (unsigned short*)(W + (64u<<20));        // 256 KB (2 layers, [64][1024])
  unsigned short* wdt_t= (unsigned short*)(W + (64u<<20) + (256u<<10)); // 128 KB
  unsigned short* wh_t = (unsigned short*)(W + (65u<<20));        // 256 KB [256][512], final_nw folded
  unsigned short* we_t = (unsigned short*)(W + (65u<<20) + (512u<<10)); // 160 KB [256][320]
  unsigned short* wp_t = (unsigned short*)(W + (66u<<20));        // 384 KB [512][384]

  unsigned short* v_b   = xs_b;  // [8192][320] bf16, frontend only
  unsigned short* cat_b = zs_b;  // [8192][384] bf16, frontend only

  // all weight preps (+norm folds) + frontend conv in ONE launch
  k_wt_all<<<4816,256,0,stream>>>(in_proj_w, out_proj_w, x_proj_w, dt_proj_w,
                                  enc_w, proj_w, act_w, comm_w, val_w,
                                  norm_w, final_nw,
                                  obs, comm_in, conv_w, conv_b,
                                  wi_t, wo_t, wx_t, wdt_t, we_t, wp_t, wh_t,
                                  v_b, cat_b);

  // frontend GEMMs
  k_gemm_enc<<<dim3(64,4),256,0,stream>>>(v_b, we_t, enc_b, cat_b);
  k_gemm_proj<<<dim3(64,8),256,0,stream>>>(cat_b, wp_t, proj_b, hb);

  for (int L=0; L<2; L++) {
    k_gemm_inproj<<<dim3(32,16),512,0,stream>>>(hb, wi_t + (size_t)L*2048*512,
                                                conv1d_w + L*1024*4, conv1d_b + L*1024, xs_b, zs_b);
    k_ssm_f<<<256,256,0,stream>>>(xs_b, zs_b, wx_t + (size_t)L*64*1024,
                                  wdt_t + (size_t)L*1024*32,
                                  dt_proj_b + L*1024, D_param + L*1024);
    k_gemm_outproj<<<dim3(64,8),256,0,stream>>>(xs_b, wo_t + (size_t)L*512*1024, hb);
  }
  k_gemm_heads<<<dim3(64,3),256,0,stream>>>(hb, wh_t, act_b, comm_b, val_b, out);
}

// Round 16
// 223.107 us; speedup vs baseline: 1.0453x; 1.0453x over previous
//
#include <hip/hip_runtime.h>
#include <math.h>

// SymNet fused model. L=1 collapses the mamba block to:
//   u = rmsnorm(h); xz = u@Wi; x = silu(xz[:,:1024]*cw[:,3]+cb); z' = silu(xz[:,1024:])
//   xdbl = x@Wx; dt = softplus(xdbl[:,:32]@Wdt + bdt); bc = dot(xdbl[:,32:48], xdbl[:,48:64])
//   g = x*(dt*bc + D) * z'; h += g@Wo
// A_log (dA) is dead code: dA multiplies h0 == 0.
// R16: revert to R14 (measured best, 224us). R15's 256-row inproj tile regressed
//      (1 block/CU at 2-phase loses cross-block latency hiding) - twice-measured.

typedef __bf16 bf16x8 __attribute__((ext_vector_type(8)));
typedef float f32x4 __attribute__((ext_vector_type(4)));
typedef short short8 __attribute__((ext_vector_type(8)));

__device__ __forceinline__ float siluf(float v){ return v / (1.f + __expf(-v)); }
__device__ __forceinline__ float spfast(float v){ return v > 15.f ? v : __logf(1.f + __expf(v)); }
__device__ __forceinline__ float b2f(unsigned short u){ return __uint_as_float(((unsigned)u)<<16); }
__device__ __forceinline__ unsigned short f2b(float f){
  unsigned u = __float_as_uint(f);
  return (unsigned short)((u + 0x7fffu + ((u>>16)&1u)) >> 16);
}
__device__ __forceinline__ void g2l16(const void* g, void* l){
  __builtin_amdgcn_global_load_lds((const __attribute__((address_space(1))) unsigned int*)g,
                                   (__attribute__((address_space(3))) unsigned int*)l, 16, 0, 0);
}

// ---------------- merged prep: weight transposes (+norm folds) + heads concat + conv ----------------
__global__ __launch_bounds__(256) void k_wt_all(
    const float* __restrict__ in_proj_w, const float* __restrict__ out_proj_w,
    const float* __restrict__ x_proj_w,  const float* __restrict__ dt_proj_w,
    const float* __restrict__ enc_w,     const float* __restrict__ proj_w,
    const float* __restrict__ act_w, const float* __restrict__ comm_w, const float* __restrict__ val_w,
    const float* __restrict__ norm_w, const float* __restrict__ final_nw,
    const float* __restrict__ obs, const float* __restrict__ comm_in,
    const float* __restrict__ conv_w, const float* __restrict__ conv_b,
    unsigned short* __restrict__ wi_t, unsigned short* __restrict__ wo_t,
    unsigned short* __restrict__ wx_t, unsigned short* __restrict__ wdt_t,
    unsigned short* __restrict__ we_t, unsigned short* __restrict__ wp_t,
    unsigned short* __restrict__ wh_t,
    unsigned short* __restrict__ v, unsigned short* __restrict__ cat)
{
  int b = blockIdx.x;
  const int t = threadIdx.x;

  // frontend prep segment: blocks 3792..4815 (1024 blocks, 8 rows each)
  if (b >= 3792) {
    __shared__ float s_obs[8][76];
    const int r0 = (b - 3792) * 8;
    for (int i = t; i < 8*75; i += 256) s_obs[i/75][i%75] = obs[(size_t)(r0 + i/75)*75 + i%75];
    __syncthreads();
    for (int i = t; i < 8*288; i += 256) {
      int r = i / 288, o = i % 288;
      int c = o / 9, ij = o % 9, oi = ij/3, oj = ij%3;
      float acc = conv_b[c];
      #pragma unroll
      for (int ic=0; ic<3; ic++)
        #pragma unroll
        for (int ki=0; ki<3; ki++)
          #pragma unroll
          for (int kj=0; kj<3; kj++)
            acc = fmaf(s_obs[r][ic*25 + (oi+ki)*5 + (oj+kj)], conv_w[((c*3+ic)*3+ki)*3+kj], acc);
      v[(size_t)(r0+r)*320 + o] = f2b(fmaxf(acc, 0.f));
    }
    v[(size_t)(r0 + (t>>5))*320 + 288 + (t&31)] = 0;  // zero pad cols 288..319
    for (int i = t; i < 8*128; i += 256) {
      int r = i >> 7, c = i & 127;
      cat[(size_t)(r0+r)*384 + 256 + c] = f2b(comm_in[(size_t)(r0+r)*128 + c]);
    }
    return;
  }
  // heads concat segment: blocks 3536..3791 (final_nw folded, fp32)
  if (b >= 3536) {
    const int n = b - 3536;
    for (int k = t; k < 512; k += 256) {
      float v2;
      if (n < 4)         v2 = act_w[k*4 + n];
      else if (n < 132)  v2 = comm_w[k*128 + (n-4)];
      else if (n == 132) v2 = val_w[k];
      else               v2 = 0.f;
      wh_t[(size_t)n*512 + k] = f2b(v2 * final_nw[k]);
    }
    return;
  }
  const float* Wsrc; unsigned short* Wdst; int Kd, Nd, KP, nkb;
  const float* nwf = nullptr;  // per-k fold factor (norm_w), or null
  if (b < 2048) {        // in_proj, 2 layers: [512][2048] -> [2048][512], norm_w folded
    const int L = b >> 10; b &= 1023;
    Wsrc = in_proj_w + (size_t)L*512*2048; Wdst = wi_t + (size_t)L*2048*512;
    Kd = 512; Nd = 2048; KP = 512; nkb = 16;
    nwf = norm_w + L*512;
  } else if (b < 3072) { // out_proj, 2 layers: [1024][512] -> [512][1024]
    b -= 2048; const int L = b >> 9; b &= 511;
    Wsrc = out_proj_w + (size_t)L*1024*512; Wdst = wo_t + (size_t)L*512*1024;
    Kd = 1024; Nd = 512; KP = 1024; nkb = 32;
  } else if (b < 3200) { // x_proj, 2 layers: [1024][64] -> [64][1024]
    b -= 3072; const int L = b >> 6; b &= 63;
    Wsrc = x_proj_w + (size_t)L*1024*64; Wdst = wx_t + (size_t)L*64*1024;
    Kd = 1024; Nd = 64; KP = 1024; nkb = 32;
  } else if (b < 3264) { // dt_proj, 2 layers: [32][1024] -> [1024][32]
    b -= 3200; const int L = b >> 5; b &= 31;
    Wsrc = dt_proj_w + (size_t)L*32*1024; Wdst = wdt_t + (size_t)L*1024*32;
    Kd = 32; Nd = 1024; KP = 32; nkb = 1;
  } else if (b < 3344) { // enc: [288][256] -> [256][320] (K padded)
    b -= 3264; Wsrc = enc_w; Wdst = we_t; Kd = 288; Nd = 256; KP = 320; nkb = 10;
  } else {               // proj: [384][512] -> [512][384]
    b -= 3344; Wsrc = proj_w; Wdst = wp_t; Kd = 384; Nd = 512; KP = 384; nkb = 12;
  }
  __shared__ float s[32][33];
  const int kb = (b % nkb)*32, nb = (b / nkb)*32;
  const int c = t & 31, r = t >> 5;
  #pragma unroll
  for (int i=0;i<32;i+=8) {
    const int k = kb + r + i;
    s[r+i][c] = (k < Kd) ? Wsrc[(size_t)k*Nd + nb + c] : 0.f;
  }
  __syncthreads();
  const float nwv = nwf ? nwf[kb + c] : 1.f;   // written value has k = kb + c
  #pragma unroll
  for (int i=0;i<32;i+=8) Wdst[(size_t)(nb+r+i)*KP + kb + c] = f2b(s[c][r+i] * nwv);
}

// ---------------- MFMA 128xNB tile mainloop, double-buffered (T3 minimum 2-phase) ----------------
template<int K, int NB>
__device__ __forceinline__ void gemmT(const unsigned short* __restrict__ A,
                                      const unsigned short* __restrict__ Bt,
                                      int r0, int c0,
                                      unsigned short* sA, unsigned short* sB,
                                      f32x4 (&acc)[4][NB/32])
{
  constexpr int NF = NB/32;
  constexpr int ABUF = 128*64, BBUF = NB*64;
  const int tid = threadIdx.x;
  const int l = tid & 63;
  const int wr = (tid>>7)&1, wc = (tid>>6)&1;
  const int rowA = tid>>3, kc8 = (tid&7)*8;
  const unsigned short* gA = A  + (size_t)(r0+rowA)*K + kc8;
  const unsigned short* gB = Bt + (size_t)(c0+rowA)*K + kc8;
  const int aOff = (wr*64 + (l&15))*64 + ((l>>4)*8);
  const int bOff = (wc*(NB/2) + (l&15))*64 + ((l>>4)*8);

  auto stage = [&](int kt, int buf) {
    #pragma unroll
    for (int it=0; it<4; ++it)
      g2l16(gA + (size_t)(it*32)*K + kt, sA + buf*ABUF + (it*256+tid)*8);
    #pragma unroll
    for (int it=0; it<NF; ++it)
      g2l16(gB + (size_t)(it*32)*K + kt, sB + buf*BBUF + (it*256+tid)*8);
  };

  stage(0, 0);
  __syncthreads();
  int cur = 0;
  for (int kt=0; kt<K; kt+=64) {
    if (kt + 64 < K) stage(kt + 64, cur ^ 1);   // in flight during MFMA below
    const unsigned short* pA = sA + cur*ABUF;
    const unsigned short* pB = sB + cur*BBUF;
    #pragma unroll
    for (int ks=0; ks<64; ks+=32) {
      bf16x8 af[4], bfm[NF];
      #pragma unroll
      for (int m=0;m<4;m++) af[m]  = *(const bf16x8*)(pA + (m*16)*64 + aOff + ks);
      #pragma unroll
      for (int n=0;n<NF;n++) bfm[n] = *(const bf16x8*)(pB + (n*16)*64 + bOff + ks);
      #pragma unroll
      for (int m=0;m<4;m++)
        #pragma unroll
        for (int n=0;n<NF;n++)
          acc[m][n] = __builtin_amdgcn_mfma_f32_16x16x32_bf16(af[m], bfm[n], acc[m][n], 0, 0, 0);
    }
    __syncthreads();
    cur ^= 1;
  }
}

// ---------------- same, plus per-row sumsq of the A panel -> s_scale[128] ----------------
template<int K, int NB>
__device__ __forceinline__ void gemmT_ss(const unsigned short* __restrict__ A,
                                         const unsigned short* __restrict__ Bt,
                                         int r0, int c0,
                                         unsigned short* sA, unsigned short* sB,
                                         f32x4 (&acc)[4][NB/32], float* s_scale)
{
  constexpr int NF = NB/32;
  constexpr int ABUF = 128*64, BBUF = NB*64;
  const int tid = threadIdx.x;
  const int l = tid & 63;
  const int wr = (tid>>7)&1, wc = (tid>>6)&1;
  const int rowA = tid>>3, kc8 = (tid&7)*8;
  const unsigned short* gA = A  + (size_t)(r0+rowA)*K + kc8;
  const unsigned short* gB = Bt + (size_t)(c0+rowA)*K + kc8;
  const int aOff = (wr*64 + (l&15))*64 + ((l>>4)*8);
  const int bOff = (wc*(NB/2) + (l&15))*64 + ((l>>4)*8);

  auto stage = [&](int kt, int buf) {
    #pragma unroll
    for (int it=0; it<4; ++it)
      g2l16(gA + (size_t)(it*32)*K + kt, sA + buf*ABUF + (it*256+tid)*8);
    #pragma unroll
    for (int it=0; it<NF; ++it)
      g2l16(gB + (size_t)(it*32)*K + kt, sB + buf*BBUF + (it*256+tid)*8);
  };

  float ss4[4] = {0.f, 0.f, 0.f, 0.f};
  stage(0, 0);
  __syncthreads();
  int cur = 0;
  for (int kt=0; kt<K; kt+=64) {
    if (kt + 64 < K) stage(kt + 64, cur ^ 1);
    const unsigned short* pA = sA + cur*ABUF;
    const unsigned short* pB = sB + cur*BBUF;
    #pragma unroll
    for (int ks=0; ks<64; ks+=32) {
      bf16x8 af[4], bfm[NF];
      #pragma unroll
      for (int m=0;m<4;m++) af[m]  = *(const bf16x8*)(pA + (m*16)*64 + aOff + ks);
      #pragma unroll
      for (int n=0;n<NF;n++) bfm[n] = *(const bf16x8*)(pB + (n*16)*64 + bOff + ks);
      #pragma unroll
      for (int m=0;m<4;m++)
        #pragma unroll
        for (int n=0;n<NF;n++)
          acc[m][n] = __builtin_amdgcn_mfma_f32_16x16x32_bf16(af[m], bfm[n], acc[m][n], 0, 0, 0);
    }
    // per-row sumsq of this K-slice (fills barrier-stall cycles)
    #pragma unroll
    for (int c2=0;c2<4;c2++){
      short8 av = *(const short8*)(pA + (tid + c2*256)*8);
      #pragma unroll
      for (int e=0;e<8;e++){ float f = b2f((unsigned short)av[e]); ss4[c2] = fmaf(f, f, ss4[c2]); }
    }
    __syncthreads();
    cur ^= 1;
  }
  #pragma unroll
  for (int c2=0;c2<4;c2++){
    #pragma unroll
    for (int msk=1; msk<8; msk<<=1) ss4[c2] += __shfl_xor(ss4[c2], msk, 64);
  }
  if ((tid & 7) == 0) {
    #pragma unroll
    for (int c2=0;c2<4;c2++)
      s_scale[(tid>>3) + c2*32] = rsqrtf(ss4[c2]*(1.f/512.f) + 1e-5f);
  }
  __syncthreads();
}

// ---------------- in_proj: hb @ (Wi*nw) -> scale s[r] -> silu/conv-collapse -> xs,zs ----------------
__global__ __launch_bounds__(256) void k_gemm_inproj(
    const unsigned short* __restrict__ A, const unsigned short* __restrict__ Bt,
    const float* __restrict__ cw, const float* __restrict__ cb,
    unsigned short* __restrict__ xs, unsigned short* __restrict__ zs)
{
  __shared__ unsigned short sA[2*128*64], sB[2*128*64];   // 32KB + 32KB
  __shared__ float s_scale[128];
  f32x4 acc[4][4];
  #pragma unroll
  for (int m=0;m<4;m++)
    #pragma unroll
    for (int n=0;n<4;n++) acc[m][n] = (f32x4){0.f,0.f,0.f,0.f};
  const int r0 = blockIdx.x*128, c0 = blockIdx.y*128;
  gemmT_ss<512,128>(A, Bt, r0, c0, sA, sB, acc, s_scale);

  const int tid = threadIdx.x, l = tid & 63;
  const int wr = (tid>>7)&1, wc = (tid>>6)&1;
  const int colB = c0 + wc*64 + (l&15);
  const int rowL = wr*64 + ((l>>4)*4);
  float sv[4][4];
  #pragma unroll
  for (int m=0;m<4;m++)
    #pragma unroll
    for (int j=0;j<4;j++) sv[m][j] = s_scale[rowL + m*16 + j];
  if (c0 < 1024) {
    #pragma unroll
    for (int n=0;n<4;n++){
      const int col = colB + n*16;
      const float cw3 = cw[col*4+3], cbv = cb[col];
      #pragma unroll
      for (int m=0;m<4;m++)
        #pragma unroll
        for (int j=0;j<4;j++){
          const int row = r0 + rowL + m*16 + j;
          xs[(size_t)row*1024 + col] = f2b(siluf(fmaf(acc[m][n][j]*sv[m][j], cw3, cbv)));
        }
    }
  } else {
    #pragma unroll
    for (int n=0;n<4;n++){
      const int col = colB + n*16 - 1024;
      #pragma unroll
      for (int m=0;m<4;m++)
        #pragma unroll
        for (int j=0;j<4;j++){
          const int row = r0 + rowL + m*16 + j;
          zs[(size_t)row*1024 + col] = f2b(siluf(acc[m][n][j]*sv[m][j]));
        }
    }
  }
}

// ---------------- out_proj: g(8192x1024) @ Wo -> hb += (fp32 add, bf16 store) ----------------
__global__ __launch_bounds__(256) void k_gemm_outproj(
    const unsigned short* __restrict__ A, const unsigned short* __restrict__ Bt,
    unsigned short* __restrict__ hb)
{
  __shared__ unsigned short sA[2*128*64], sB[2*64*64];
  f32x4 acc[4][2];
  #pragma unroll
  for (int m=0;m<4;m++)
    #pragma unroll
    for (int n=0;n<2;n++) acc[m][n] = (f32x4){0.f,0.f,0.f,0.f};
  const int r0 = blockIdx.x*128, c0 = blockIdx.y*64;
  gemmT<1024,64>(A, Bt, r0, c0, sA, sB, acc);

  const int tid = threadIdx.x, l = tid & 63;
  const int wr = (tid>>7)&1, wc = (tid>>6)&1;
  const int colB = c0 + wc*32 + (l&15);
  const int rowB = r0 + wr*64 + ((l>>4)*4);
  #pragma unroll
  for (int n=0;n<2;n++){
    const int col = colB + n*16;
    #pragma unroll
    for (int m=0;m<4;m++)
      #pragma unroll
      for (int j=0;j<4;j++){
        const int row = rowB + m*16 + j;
        float hv = b2f(hb[(size_t)row*512 + col]) + acc[m][n][j];
        hb[(size_t)row*512 + col] = f2b(hv);
      }
  }
}

// ---------------- frontend GEMM1: v(8192x320) @ enc_t^T -> relu -> cat[:, :256] (BN=64) ----------------
__global__ __launch_bounds__(256) void k_gemm_enc(
    const unsigned short* __restrict__ A, const unsigned short* __restrict__ Bt,
    const float* __restrict__ bias, unsigned short* __restrict__ cat)
{
  __shared__ unsigned short sA[2*128*64], sB[2*64*64];
  f32x4 acc[4][2];
  #pragma unroll
  for (int m=0;m<4;m++)
    #pragma unroll
    for (int n=0;n<2;n++) acc[m][n] = (f32x4){0.f,0.f,0.f,0.f};
  const int r0 = blockIdx.x*128, c0 = blockIdx.y*64;
  gemmT<320,64>(A, Bt, r0, c0, sA, sB, acc);

  const int tid = threadIdx.x, l = tid & 63;
  const int wr = (tid>>7)&1, wc = (tid>>6)&1;
  const int colB = c0 + wc*32 + (l&15);
  const int rowB = r0 + wr*64 + ((l>>4)*4);
  #pragma unroll
  for (int n=0;n<2;n++){
    const int col = colB + n*16;
    const float bv = bias[col];
    #pragma unroll
    for (int m=0;m<4;m++)
      #pragma unroll
      for (int j=0;j<4;j++){
        const size_t row = rowB + m*16 + j;
        cat[row*384 + col] = f2b(fmaxf(acc[m][n][j] + bv, 0.f));
      }
  }
}

// ---------------- frontend GEMM2: cat(8192x384) @ proj_t^T -> relu -> hb bf16 (BN=64) ----------------
__global__ __launch_bounds__(256) void k_gemm_proj(
    const unsigned short* __restrict__ A, const unsigned short* __restrict__ Bt,
    const float* __restrict__ bias, unsigned short* __restrict__ hb)
{
  __shared__ unsigned short sA[2*128*64], sB[2*64*64];
  f32x4 acc[4][2];
  #pragma unroll
  for (int m=0;m<4;m++)
    #pragma unroll
    for (int n=0;n<2;n++) acc[m][n] = (f32x4){0.f,0.f,0.f,0.f};
  const int r0 = blockIdx.x*128, c0 = blockIdx.y*64;
  gemmT<384,64>(A, Bt, r0, c0, sA, sB, acc);

  const int tid = threadIdx.x, l = tid & 63;
  const int wr = (tid>>7)&1, wc = (tid>>6)&1;
  const int colB = c0 + wc*32 + (l&15);
  const int rowB = r0 + wr*64 + ((l>>4)*4);
  #pragma unroll
  for (int n=0;n<2;n++){
    const int col = colB + n*16;
    const float bv = bias[col];
    #pragma unroll
    for (int m=0;m<4;m++)
      #pragma unroll
      for (int j=0;j<4;j++){
        const size_t row = rowB + m*16 + j;
        hb[row*512 + col] = f2b(fmaxf(acc[m][n][j] + bv, 0.f));
      }
  }
}

// ---------------- heads GEMM: hb @ (Wh*fnw)^T -> scale s[r] -> act/tanh/val scatter ----------------
__global__ __launch_bounds__(256) void k_gemm_heads(
    const unsigned short* __restrict__ A, const unsigned short* __restrict__ Bt,
    const float* __restrict__ act_b, const float* __restrict__ comm_b,
    const float* __restrict__ val_b, float* __restrict__ out)
{
  __shared__ unsigned short sA[2*128*64], sB[2*64*64];
  __shared__ float s_scale[128];
  f32x4 acc[4][2];
  #pragma unroll
  for (int m=0;m<4;m++)
    #pragma unroll
    for (int n=0;n<2;n++) acc[m][n] = (f32x4){0.f,0.f,0.f,0.f};
  const int r0 = blockIdx.x*128, c0 = blockIdx.y*64;
  gemmT_ss<512,64>(A, Bt, r0, c0, sA, sB, acc, s_scale);

  const int tid = threadIdx.x, l = tid & 63;
  const int wr = (tid>>7)&1, wc = (tid>>6)&1;
  const int colB = c0 + wc*32 + (l&15);
  const int rowL = wr*64 + ((l>>4)*4);
  #pragma unroll
  for (int n=0;n<2;n++){
    const int col = colB + n*16;
    if (col > 132) continue;
    #pragma unroll
    for (int m=0;m<4;m++)
      #pragma unroll
      for (int j=0;j<4;j++){
        const size_t row = r0 + rowL + m*16 + j;
        float v = acc[m][n][j] * s_scale[rowL + m*16 + j];
        if (col < 4)        out[row*4 + col] = v + act_b[col];
        else if (col < 132) out[32768 + row*128 + (col-4)] = tanhf(v + comm_b[col-4]);
        else                out[1081344 + row] = v + val_b[0];
      }
  }
}

// ---------------- fused SSM: x_dbl GEMM + bc + dt GEMM + gate, 32 rows/block (dbuf both phases) ----------------
__global__ __launch_bounds__(256) void k_ssm_f(
    unsigned short* __restrict__ xs, const unsigned short* __restrict__ zs,
    const unsigned short* __restrict__ Wx_t, const unsigned short* __restrict__ Wdt_t,
    const float* __restrict__ bdt, const float* __restrict__ Dp)
{
  __shared__ unsigned short sX[32*1024];   // 64KB: xs rows, bf16
  __shared__ unsigned short sB[2*64*128];  // 32KB: Wx chunks (ph1) / Wdt chunks [256][32] (ph2), dbuf
  __shared__ float s_dbl[32][64];          //  8KB
  __shared__ unsigned short sDt[32*32];    //  2KB
  __shared__ float s_bc[32];
  constexpr int BB = 64*128;
  const int tid = threadIdx.x, l = tid & 63, w = tid >> 6;
  const int r0 = blockIdx.x * 32;

  auto stageWx = [&](int kt, int buf) {
    #pragma unroll
    for (int it=0; it<4; ++it) {               // 64 rows x 128 k
      const int idx = it*256 + tid;
      g2l16(Wx_t + (size_t)(idx>>4)*1024 + (idx&15)*8 + kt, sB + buf*BB + idx*8);
    }
  };

  // stage all 32 xs rows (16 iters x 256 threads x 16B) + first Wx chunk
  #pragma unroll
  for (int it=0; it<16; ++it) {
    const int idx = it*256 + tid;              // row = idx>>7, col8 = (idx&127)*8
    g2l16(xs + (size_t)(r0 + (idx>>7))*1024 + (idx&127)*8, sX + idx*8);
  }
  stageWx(0, 0);
  __syncthreads();

  // ---- phase 1: x_dbl = xs @ Wx_t^T (64 cols; wave w owns cols w*16..w*16+15) ----
  f32x4 acc0 = (f32x4){0.f,0.f,0.f,0.f}, acc1 = (f32x4){0.f,0.f,0.f,0.f};
  int cur = 0;
  for (int kt = 0; kt < 1024; kt += 128) {
    if (kt + 128 < 1024) stageWx(kt + 128, cur ^ 1);
    const unsigned short* pB = sB + cur*BB;
    #pragma unroll
    for (int ks=0; ks<128; ks+=32) {
      bf16x8 a0 = *(const bf16x8*)(sX + ((l&15))*1024    + (l>>4)*8 + kt + ks);
      bf16x8 a1 = *(const bf16x8*)(sX + (16+(l&15))*1024 + (l>>4)*8 + kt + ks);
      bf16x8 bf = *(const bf16x8*)(pB + (w*16+(l&15))*128 + (l>>4)*8 + ks);
      acc0 = __builtin_amdgcn_mfma_f32_16x16x32_bf16(a0, bf, acc0, 0, 0, 0);
      acc1 = __builtin_amdgcn_mfma_f32_16x16x32_bf16(a1, bf, acc1, 0, 0, 0);
    }
    __syncthreads();
    cur ^= 1;
  }

  // stage first Wdt chunk early (hides under the s_dbl/bc/sDt work)
  auto stageWdt = [&](int c, int buf) {
    const int cc = c*256;
    #pragma unroll
    for (int it=0; it<4; ++it) {               // 256 rows x 32 k = 16KB
      const int idx = it*256 + tid;            // row = idx>>2, col8 = (idx&3)*8
      g2l16(Wdt_t + (size_t)(cc + (idx>>2))*32 + (idx&3)*8, sB + buf*BB + idx*8);
    }
  };
  stageWdt(0, 0);

  #pragma unroll
  for (int j=0;j<4;j++) {
    s_dbl[(l>>4)*4 + j]     [w*16 + (l&15)] = acc0[j];
    s_dbl[16 + (l>>4)*4 + j][w*16 + (l&15)] = acc1[j];
  }
  __syncthreads();
  if (tid < 32) {          // bc[row] = dot(xdbl[row][32:48], xdbl[row][48:64])
    float a = 0.f;
    #pragma unroll
    for (int s=0;s<16;s++) a = fmaf(s_dbl[tid][32+s], s_dbl[tid][48+s], a);
    s_bc[tid] = a;
  }
  { // dt_in bf16 [32][32]
    const int r = tid >> 3, c4 = (tid & 7)*4;
    sDt[r*32 + c4]   = f2b(s_dbl[r][c4]);
    sDt[r*32 + c4+1] = f2b(s_dbl[r][c4+1]);
    sDt[r*32 + c4+2] = f2b(s_dbl[r][c4+2]);
    sDt[r*32 + c4+3] = f2b(s_dbl[r][c4+3]);
  }
  __syncthreads();

  // ---- phase 2: dt GEMM (K=32) + gate, 4 chunks of 256 cols; wave w owns 64 cols/chunk ----
  bf16x8 af0 = *(const bf16x8*)(sDt + ((l&15))*32    + (l>>4)*8);
  bf16x8 af1 = *(const bf16x8*)(sDt + (16+(l&15))*32 + (l>>4)*8);
  for (int c = 0; c < 4; ++c) {
    if (c + 1 < 4) stageWdt(c + 1, (c + 1) & 1);
    const unsigned short* pB = sB + (c & 1)*BB;
    f32x4 a2[2][4];
    #pragma unroll
    for (int n=0;n<4;n++){
      bf16x8 bn = *(const bf16x8*)(pB + (w*64 + n*16 + (l&15))*32 + (l>>4)*8);
      a2[0][n] = __builtin_amdgcn_mfma_f32_16x16x32_bf16(af0, bn, (f32x4){0.f,0.f,0.f,0.f}, 0, 0, 0);
      a2[1][n] = __builtin_amdgcn_mfma_f32_16x16x32_bf16(af1, bn, (f32x4){0.f,0.f,0.f,0.f}, 0, 0, 0);
    }
    const int cc = c*256;
    #pragma unroll
    for (int n=0;n<4;n++){
      const int col = cc + w*64 + n*16 + (l&15);
      const float bj = bdt[col], dpj = Dp[col];
      #pragma unroll
      for (int m=0;m<2;m++){
        #pragma unroll
        for (int j=0;j<4;j++){
          const int rloc = m*16 + (l>>4)*4 + j;
          const size_t row = r0 + rloc;
          const float dtv = spfast(a2[m][n][j] + bj);
          const float f = fmaf(dtv, s_bc[rloc], dpj);
          const float x = b2f(sX[rloc*1024 + col]);
          const float z = b2f(zs[row*1024 + col]);
          xs[row*1024 + col] = f2b(x * f * z);
        }
      }
    }
    __syncthreads();
  }
}

extern "C" void kernel_launch(void* const* d_in, const int* in_sizes, int n_in,
                              void* d_out, int out_size, void* d_ws, size_t ws_size,
                              hipStream_t stream) {
  const float* obs       = (const float*)d_in[0];
  const float* comm_in   = (const float*)d_in[1];
  const float* conv_w    = (const float*)d_in[2];
  const float* conv_b    = (const float*)d_in[3];
  const float* enc_w     = (const float*)d_in[4];
  const float* enc_b     = (const float*)d_in[5];
  const float* proj_w    = (const float*)d_in[6];
  const float* proj_b    = (const float*)d_in[7];
  const float* norm_w    = (const float*)d_in[8];
  const float* in_proj_w = (const float*)d_in[9];
  const float* conv1d_w  = (const float*)d_in[10];
  const float* conv1d_b  = (const float*)d_in[11];
  const float* x_proj_w  = (const float*)d_in[12];
  const float* dt_proj_w = (const float*)d_in[13];
  const float* dt_proj_b = (const float*)d_in[14];
  // d_in[15] = A_log: dead at L=1
  const float* D_param   = (const float*)d_in[16];
  const float* out_proj_w= (const float*)d_in[17];
  const float* final_nw  = (const float*)d_in[18];
  const float* act_w     = (const float*)d_in[19];
  const float* act_b     = (const float*)d_in[20];
  const float* comm_w    = (const float*)d_in[21];
  const float* comm_b    = (const float*)d_in[22];
  const float* val_w     = (const float*)d_in[23];
  const float* val_b     = (const float*)d_in[24];
  float* out = (float*)d_out;

  char* W = (char*)d_ws;
  unsigned short* hb   = (unsigned short*)(W + (16u<<20));        //  8 MB bf16 residual h
  unsigned short* xs_b = (unsigned short*)(W + (24u<<20));        // 16 MB (reused as g; v_b during frontend)
  unsigned short* zs_b = (unsigned short*)(W + (40u<<20));        // 16 MB (cat_b during frontend)
  unsigned short* wi_t = (unsigned short*)(W + (56u<<20));        //  4 MB (2 layers, [2048][512], norm folded)
  unsigned short* wo_t = (unsigned short*)(W + (60u<<20));        //  2 MB (2 layers, [512][1024])
  unsigned short* wx_t = (unsigned short*)(W + (64u<<20));        // 256 KB (2 layers, [64][1024])
  unsigned short* wdt_t= (unsigned short*)(W + (64u<<20) + (256u<<10)); // 128 KB
  unsigned short* wh_t = (unsigned short*)(W + (65u<<20));        // 256 KB [256][512], final_nw folded
  unsigned short* we_t = (unsigned short*)(W + (65u<<20) + (512u<<10)); // 160 KB [256][320]
  unsigned short* wp_t = (unsigned short*)(W + (66u<<20));        // 384 KB [512][384]

  unsigned short* v_b   = xs_b;  // [8192][320] bf16, frontend only
  unsigned short* cat_b = zs_b;  // [8192][384] bf16, frontend only

  // all weight preps (+norm folds) + frontend conv in ONE launch
  k_wt_all<<<4816,256,0,stream>>>(in_proj_w, out_proj_w, x_proj_w, dt_proj_w,
                                  enc_w, proj_w, act_w, comm_w, val_w,
                                  norm_w, final_nw,
                                  obs, comm_in, conv_w, conv_b,
                                  wi_t, wo_t, wx_t, wdt_t, we_t, wp_t, wh_t,
                                  v_b, cat_b);

  // frontend GEMMs
  k_gemm_enc<<<dim3(64,4),256,0,stream>>>(v_b, we_t, enc_b, cat_b);
  k_gemm_proj<<<dim3(64,8),256,0,stream>>>(cat_b, wp_t, proj_b, hb);

  for (int L=0; L<2; L++) {
    k_gemm_inproj<<<dim3(64,16),256,0,stream>>>(hb, wi_t + (size_t)L*2048*512,
                                                conv1d_w + L*1024*4, conv1d_b + L*1024, xs_b, zs_b);
    k_ssm_f<<<256,256,0,stream>>>(xs_b, zs_b, wx_t + (size_t)L*64*1024,
                                  wdt_t + (size_t)L*1024*32,
                                  dt_proj_b + L*1024, D_param + L*1024);
    k_gemm_outproj<<<dim3(64,8),256,0,stream>>>(xs_b, wo_t + (size_t)L*512*1024, hb);
  }
  k_gemm_heads<<<dim3(64,3),256,0,stream>>>(hb, wh_t, act_b, comm_b, val_b, out);
}